// Round 8
// baseline (382.897 us; speedup 1.0000x reference)
//
#include <hip/hip_runtime.h>
#include <hip/hip_bf16.h>

#define NEG_SLOPE 0.2f
#define BN_RS 0.9999950000374997f   // 1/sqrt(1 + 1e-5)

typedef __attribute__((ext_vector_type(8))) _Float16 f16x8;  // MFMA A/B frag (4 VGPR)
typedef __attribute__((ext_vector_type(2))) _Float16 f16x2;
typedef __attribute__((ext_vector_type(4))) float f32x4;     // MFMA acc

// split fp32 -> fp16 hi (RNE) + fp16 lo (RNE of residual); hi+lo carries ~22 bits
__device__ __forceinline__ void store_split(float w, _Float16* H, _Float16* L, size_t off) {
  _Float16 h = (_Float16)w;
  H[off] = h;
  L[off] = (_Float16)(w - (float)h);
}

// ---------------- CSR build: two-level bucket radix (bucket = dst>>8) ----------------
// Requires N <= 65536 (dst and src packed into 16 bits each). N = 50000 here.
// csr entry = (dst<<16) | src.

__global__ void zero256(int* p) { p[threadIdx.x] = 0; }

__global__ void eb_hist(const int* __restrict__ ei, int* __restrict__ bucketSize, int E) {
  __shared__ int h[256];
  int tid = threadIdx.x;
  h[tid] = 0;
  __syncthreads();
  for (int i = blockIdx.x * 256 + tid; i < E; i += gridDim.x * 256)
    atomicAdd(&h[ei[E + i] >> 8], 1);
  __syncthreads();
  if (h[tid]) atomicAdd(&bucketSize[tid], h[tid]);
}

__global__ void eb_scan(const int* __restrict__ bucketSize, int* __restrict__ edgeStart,
                        int* __restrict__ cursor, int* __restrict__ csrStart, int N) {
  __shared__ int sd[256];
  int tid = threadIdx.x;
  int v = bucketSize[tid];
  sd[tid] = v;
  __syncthreads();
  for (int off = 1; off < 256; off <<= 1) {
    int t = (tid >= off) ? sd[tid - off] : 0;
    __syncthreads();
    sd[tid] += t;
    __syncthreads();
  }
  int excl = sd[tid] - v;
  edgeStart[tid] = excl;
  cursor[tid] = excl;
  csrStart[tid] = excl + min(tid << 8, N);
  if (tid == 255) edgeStart[256] = sd[255];
}

#define PCH 4096
__global__ __launch_bounds__(256) void eb_part(const int* __restrict__ ei,
                                               int* __restrict__ cursor,
                                               unsigned* __restrict__ staging, int E) {
  __shared__ unsigned val[PCH];
  __shared__ unsigned char bk[PCH];
  __shared__ int cnt[256];
  __shared__ int base[256];
  int tid = threadIdx.x;
  cnt[tid] = 0;
  __syncthreads();
  int e0 = blockIdx.x * PCH;
  int n = min(PCH, E - e0);
  for (int j = tid; j < n; j += 256) {
    int s = ei[e0 + j], d = ei[E + e0 + j];
    val[j] = ((unsigned)(d & 255) << 16) | (unsigned)s;
    int b = d >> 8;
    bk[j] = (unsigned char)b;
    atomicAdd(&cnt[b], 1);
  }
  __syncthreads();
  if (cnt[tid]) base[tid] = atomicAdd(&cursor[tid], cnt[tid]);
  __syncthreads();
  for (int j = tid; j < n; j += 256) {
    int b = bk[j];
    int off = atomicSub(&cnt[b], 1) - 1;
    staging[base[b] + off] = val[j];
  }
}

__global__ __launch_bounds__(256) void eb_csr(
    const unsigned* __restrict__ staging, const int* __restrict__ edgeStart,
    const int* __restrict__ csrStart, int* __restrict__ rowptr,
    unsigned* __restrict__ csr, int N) {
  __shared__ int deg[256];
  __shared__ int sc[256];
  __shared__ int ex[256];
  int b = blockIdx.x, tid = threadIdx.x;
  int n0 = b << 8;
  int nn = min(256, N - n0);
  deg[tid] = (tid < nn) ? 1 : 0;   // self-loop
  __syncthreads();
  int s0 = edgeStart[b], s1 = edgeStart[b + 1];
  for (int j = s0 + tid; j < s1; j += 256)
    atomicAdd(&deg[staging[j] >> 16], 1);
  __syncthreads();
  int dv = deg[tid];
  sc[tid] = dv;
  __syncthreads();
  for (int off = 1; off < 256; off <<= 1) {
    int t = (tid >= off) ? sc[tid - off] : 0;
    __syncthreads();
    sc[tid] += t;
    __syncthreads();
  }
  int incl = sc[tid];
  int cbase = csrStart[b];
  ex[tid] = incl - dv;
  if (tid < nn) {
    rowptr[n0 + tid + 1] = cbase + incl;
    unsigned me = (unsigned)(n0 + tid);
    csr[cbase + incl - 1] = (me << 16) | me;   // self-loop at end of row
  }
  if (b == 0 && tid == 0) rowptr[0] = 0;
  deg[tid] = 0;                          // reuse as per-node cursor
  __syncthreads();
  for (int j = s0 + tid; j < s1; j += 256) {
    unsigned v = staging[j];
    int dl = v >> 16;
    unsigned src = v & 0xFFFF;
    int off = atomicAdd(&deg[dl], 1);
    csr[cbase + ex[dl] + off] = ((unsigned)(n0 + dl) << 16) | src;
  }
}

// ---------------- per-edge softmax weights (edge-flat, latency-tolerant) ----------------
// thread i: slot = i>>2, head = i&3. w = exp(leaky(es[src]+ed[dst])).
__global__ __launch_bounds__(256) void wq_comp(
    const unsigned* __restrict__ csr, const float* __restrict__ es,
    const float* __restrict__ ed, float* __restrict__ wq, int S4) {
  int i = blockIdx.x * 256 + threadIdx.x;
  if (i >= S4) return;
  int slot = i >> 2, head = i & 3;
  unsigned v = csr[slot];
  int s = v & 0xFFFF, d = v >> 16;
  float t = es[s * 4 + head] + ed[d * 4 + head];
  t = t > 0.f ? t : NEG_SLOPE * t;
  wq[i] = __expf(t);
}

// ---------------- weight prep ----------------
// conv W[128][128] -> Wt hi/lo fp16 [144][128]: rows 0..127 = W^T split,
// rows 128..131 = combined attn-src cols (es = A @ ws), 132..135 attn-dst, 136..143 zero.
// M1 [128][64] -> [64][128]; M2 [64][128] -> [128][64].
__device__ __forceinline__ void wprep_conv(const float* __restrict__ W,
                                           const float* __restrict__ as_,
                                           const float* __restrict__ ad_,
                                           _Float16* __restrict__ H, _Float16* __restrict__ L,
                                           int lb, int tid) {
  if (lb < 64) {                       // transpose region
    int idx = lb * 256 + tid;
    int k = idx >> 7, p = idx & 127;
    store_split(W[k * 128 + p], H, L, (size_t)p * 128 + k);
  } else if (lb < 68) {                // attn-combined rows
    int idx = (lb - 64) * 256 + tid;   // 1024 entries: 8 rows x 128 k
    int rl = idx >> 7, k = idx & 127;
    const float* a = (rl < 4) ? as_ : ad_;
    int h = rl & 3;
    float s = 0.f;
#pragma unroll
    for (int f = 0; f < 32; f++) s += W[k * 128 + h * 32 + f] * a[h * 32 + f];
    store_split(s, H, L, (size_t)(128 + rl) * 128 + k);
  } else {                             // zero pad rows 136..143
    int idx = (lb - 68) * 256 + tid;
    int rl = idx >> 7, k = idx & 127;
    H[(size_t)(136 + rl) * 128 + k] = (_Float16)0.f;
    L[(size_t)(136 + rl) * 128 + k] = (_Float16)0.f;
  }
}

__global__ void wprep_all(
    const float* __restrict__ W1, const float* __restrict__ a1s, const float* __restrict__ a1d,
    _Float16* __restrict__ W1H, _Float16* __restrict__ W1L,
    const float* __restrict__ W2, const float* __restrict__ a2s, const float* __restrict__ a2d,
    _Float16* __restrict__ W2H, _Float16* __restrict__ W2L,
    const float* __restrict__ W3, const float* __restrict__ a3s, const float* __restrict__ a3d,
    _Float16* __restrict__ W3H, _Float16* __restrict__ W3L,
    const float* __restrict__ M1, _Float16* __restrict__ M1H, _Float16* __restrict__ M1L,
    const float* __restrict__ M2, _Float16* __restrict__ M2H, _Float16* __restrict__ M2L) {
  int b = blockIdx.x, tid = threadIdx.x;
  if (b < 72)       wprep_conv(W1, a1s, a1d, W1H, W1L, b, tid);
  else if (b < 144) wprep_conv(W2, a2s, a2d, W2H, W2L, b - 72, tid);
  else if (b < 216) wprep_conv(W3, a3s, a3d, W3H, W3L, b - 144, tid);
  else if (b < 248) {                  // M1: [128][64] -> [64][128]
    int idx = (b - 216) * 256 + tid;
    int k = idx >> 6, p = idx & 63;
    store_split(M1[k * 64 + p], M1H, M1L, (size_t)p * 128 + k);
  } else {                             // M2: [64][128] -> [128][64]
    int idx = (b - 248) * 256 + tid;
    int k = idx >> 7, p = idx & 127;
    store_split(M2[k * 128 + p], M2H, M2L, (size_t)p * 64 + k);
  }
}

// ---------------- GEMM via fp16 MFMA, W split hi/lo ----------------
// C[N x PST](fp16) = A[N x K] @ W; A fp16 (or fp32 for layer 0, cvt in staging).
// D = A@Wh + A@Wl. AUG=1: PT=PST+16, extra tile -> es/ed fp32 (attn scores fused).
// EPI 0: raw store. EPI 1: bn(relu(acc + bias)).
template <int PT, int PST, int K, int EPI, int AUG, typename TA>
__global__ __launch_bounds__(256) void gemm_f16(
    const TA* __restrict__ A, const _Float16* __restrict__ WtH,
    const _Float16* __restrict__ WtL, _Float16* __restrict__ C, int N,
    const float* __restrict__ bias, const float* __restrict__ gamma,
    const float* __restrict__ beta, float* __restrict__ esb,
    float* __restrict__ edb) {
  constexpr int NTILE = PT / 16;
  constexpr int CTB = NTILE / 4;      // base col-tiles per wave
  constexpr int REM = NTILE % 4;      // 0 or 1 (extra tile on wave 0)
  constexpr int KT = K / 32;
  __shared__ _Float16 As[128 * 32];
  __shared__ _Float16 WsH[PT * 32];
  __shared__ _Float16 WsL[PT * 32];
  const int tid = threadIdx.x;
  const int wave = tid >> 6, lane = tid & 63;
  const int quad = lane >> 4, l16 = lane & 15;
  const int row0 = blockIdx.x * 128;
  const bool xw = (REM != 0) && (wave == 0);

  f32x4 acc[8][CTB + (REM ? 1 : 0)];
#pragma unroll
  for (int rt = 0; rt < 8; rt++)
#pragma unroll
    for (int nt = 0; nt < CTB + (REM ? 1 : 0); nt++) acc[rt][nt] = (f32x4){0.f, 0.f, 0.f, 0.f};

  for (int kc = 0; kc < KT; ++kc) {
    // ---- stage A: 128 rows x 32 halves ----
    {
      int r = tid >> 1, part = tid & 1;
      int gr = row0 + r;
      _Float16* dst = &As[r * 32 + part * 16];
      if (gr < N) {
        const TA* src = A + (size_t)gr * K + kc * 32 + part * 16;
        if constexpr (sizeof(TA) == 4) {     // fp32 input (layer 0): cvt
          f16x8 h0, h1;
#pragma unroll
          for (int j = 0; j < 8; j++) { h0[j] = (_Float16)src[j]; h1[j] = (_Float16)src[8 + j]; }
          *(f16x8*)dst = h0; *(f16x8*)(dst + 8) = h1;
        } else {                              // fp16: raw copy
          uint4 v0 = *(const uint4*)src;
          uint4 v1 = *(const uint4*)(src + 8);
          *(uint4*)dst = v0; *(uint4*)(dst + 8) = v1;
        }
      } else {
        *(uint4*)dst = make_uint4(0, 0, 0, 0);
        *(uint4*)(dst + 8) = make_uint4(0, 0, 0, 0);
      }
    }
    // ---- stage W hi/lo: PT rows x 32 halves each ----
    for (int idx = tid; idx < PT * 2; idx += 256) {
      int isL = idx >= PT;
      int p = isL ? idx - PT : idx;
      const _Float16* src = (isL ? WtL : WtH) + (size_t)p * K + kc * 32;
      _Float16* dst = (isL ? WsL : WsH) + p * 32;
      uint4 a0 = *(const uint4*)src;       uint4 a1 = *(const uint4*)(src + 8);
      uint4 a2 = *(const uint4*)(src + 16); uint4 a3 = *(const uint4*)(src + 24);
      *(uint4*)dst = a0; *(uint4*)(dst + 8) = a1;
      *(uint4*)(dst + 16) = a2; *(uint4*)(dst + 24) = a3;
    }
    __syncthreads();

    f16x8 bh[CTB], bl[CTB], bhE, blE;
#pragma unroll
    for (int nt = 0; nt < CTB; nt++) {
      int p = (wave * CTB + nt) * 16 + l16;
      bh[nt] = *(f16x8*)&WsH[p * 32 + quad * 8];
      bl[nt] = *(f16x8*)&WsL[p * 32 + quad * 8];
    }
    if constexpr (REM) {
      if (xw) {
        int p = 4 * CTB * 16 + l16;
        bhE = *(f16x8*)&WsH[p * 32 + quad * 8];
        blE = *(f16x8*)&WsL[p * 32 + quad * 8];
      }
    }
#pragma unroll
    for (int rt = 0; rt < 8; rt++) {
      f16x8 a = *(f16x8*)&As[(rt * 16 + l16) * 32 + quad * 8];
#pragma unroll
      for (int nt = 0; nt < CTB; nt++) {
        acc[rt][nt] = __builtin_amdgcn_mfma_f32_16x16x32_f16(a, bh[nt], acc[rt][nt], 0, 0, 0);
        acc[rt][nt] = __builtin_amdgcn_mfma_f32_16x16x32_f16(a, bl[nt], acc[rt][nt], 0, 0, 0);
      }
      if constexpr (REM) {
        if (xw) {
          acc[rt][CTB] = __builtin_amdgcn_mfma_f32_16x16x32_f16(a, bhE, acc[rt][CTB], 0, 0, 0);
          acc[rt][CTB] = __builtin_amdgcn_mfma_f32_16x16x32_f16(a, blE, acc[rt][CTB], 0, 0, 0);
        }
      }
    }
    __syncthreads();
  }

  // ---- epilogue (C/D layout: col=lane&15, row=quad*4+reg) ----
#pragma unroll
  for (int nt = 0; nt < CTB; nt++) {
    int c = (wave * CTB + nt) * 16 + l16;
    float bi = 0.f, ga = 0.f, be = 0.f;
    if constexpr (EPI == 1) { bi = bias[c]; ga = gamma[c] * BN_RS; be = beta[c]; }
#pragma unroll
    for (int rt = 0; rt < 8; rt++)
#pragma unroll
      for (int g = 0; g < 4; g++) {
        int r = row0 + rt * 16 + quad * 4 + g;
        if (r < N) {
          float v = acc[rt][nt][g];
          if constexpr (EPI == 1) { v += bi; v = v > 0.f ? v : 0.f; v = v * ga + be; }
          C[(size_t)r * PST + c] = (_Float16)v;
        }
      }
  }
  if constexpr (REM) {
    if (wave == 0 && l16 < 8) {
      float* dstb = (l16 < 4) ? esb : edb;
      int h = l16 & 3;
#pragma unroll
      for (int rt = 0; rt < 8; rt++)
#pragma unroll
        for (int g = 0; g < 4; g++) {
          int r = row0 + rt * 16 + quad * 4 + g;
          if (r < N) dstb[(size_t)r * 4 + h] = acc[rt][CTB][g];
        }
    }
  }
}

// ---------------- GAT aggregation: one wave per dst node ----------------
// Weights precomputed in wq (fp32, [slot][4]). Inner loop is dependency-depth-1:
// 8-wide unrolled hv gathers (8 loads in flight per wave).
// lane i holds features (2i, 2i+1); head = i>>4.
// MODE 0: out fp16 [N,128] = relu(S/z + bias). MODE 1: out fp32 [N,32] = mean_heads + bias.
template <int MODE>
__global__ __launch_bounds__(256) void gat_agg(
    const _Float16* __restrict__ hx, const int* __restrict__ rowptr,
    const unsigned* __restrict__ csr, const float* __restrict__ wq,
    const float* __restrict__ bias, void* __restrict__ outp, int N) {
  int wid = (blockIdx.x * 256 + threadIdx.x) >> 6;
  if (wid >= N) return;
  int lane = threadIdx.x & 63;
  int head = lane >> 4;
  int beg = rowptr[wid], end = rowptr[wid + 1];
  float ax = 0.f, ay = 0.f, z = 0.f;
  const _Float16* hb = hx + 2 * lane;

  int e = beg;
  for (; e + 8 <= end; e += 8) {
    unsigned v0 = csr[e], v1 = csr[e + 1], v2 = csr[e + 2], v3 = csr[e + 3];
    unsigned v4 = csr[e + 4], v5 = csr[e + 5], v6 = csr[e + 6], v7 = csr[e + 7];
    float w0 = wq[(e + 0) * 4 + head], w1 = wq[(e + 1) * 4 + head];
    float w2 = wq[(e + 2) * 4 + head], w3 = wq[(e + 3) * 4 + head];
    float w4 = wq[(e + 4) * 4 + head], w5 = wq[(e + 5) * 4 + head];
    float w6 = wq[(e + 6) * 4 + head], w7 = wq[(e + 7) * 4 + head];
    f16x2 h0 = *(const f16x2*)(hb + (size_t)(v0 & 0xFFFF) * 128);
    f16x2 h1 = *(const f16x2*)(hb + (size_t)(v1 & 0xFFFF) * 128);
    f16x2 h2 = *(const f16x2*)(hb + (size_t)(v2 & 0xFFFF) * 128);
    f16x2 h3 = *(const f16x2*)(hb + (size_t)(v3 & 0xFFFF) * 128);
    f16x2 h4 = *(const f16x2*)(hb + (size_t)(v4 & 0xFFFF) * 128);
    f16x2 h5 = *(const f16x2*)(hb + (size_t)(v5 & 0xFFFF) * 128);
    f16x2 h6 = *(const f16x2*)(hb + (size_t)(v6 & 0xFFFF) * 128);
    f16x2 h7 = *(const f16x2*)(hb + (size_t)(v7 & 0xFFFF) * 128);
    z += ((w0 + w1) + (w2 + w3)) + ((w4 + w5) + (w6 + w7));
    ax = fmaf(w0, (float)h0[0], ax); ay = fmaf(w0, (float)h0[1], ay);
    ax = fmaf(w1, (float)h1[0], ax); ay = fmaf(w1, (float)h1[1], ay);
    ax = fmaf(w2, (float)h2[0], ax); ay = fmaf(w2, (float)h2[1], ay);
    ax = fmaf(w3, (float)h3[0], ax); ay = fmaf(w3, (float)h3[1], ay);
    ax = fmaf(w4, (float)h4[0], ax); ay = fmaf(w4, (float)h4[1], ay);
    ax = fmaf(w5, (float)h5[0], ax); ay = fmaf(w5, (float)h5[1], ay);
    ax = fmaf(w6, (float)h6[0], ax); ay = fmaf(w6, (float)h6[1], ay);
    ax = fmaf(w7, (float)h7[0], ax); ay = fmaf(w7, (float)h7[1], ay);
  }
  for (; e < end; ++e) {
    unsigned v = csr[e];
    float w = wq[e * 4 + head];
    f16x2 hv = *(const f16x2*)(hb + (size_t)(v & 0xFFFF) * 128);
    z += w;
    ax = fmaf(w, (float)hv[0], ax);
    ay = fmaf(w, (float)hv[1], ay);
  }
  float inv = 1.f / (z + 1e-16f);
  float vx = ax * inv, vy = ay * inv;
  if (MODE == 0) {
    vx += bias[2 * lane]; vy += bias[2 * lane + 1];
    vx = vx > 0.f ? vx : 0.f;  vy = vy > 0.f ? vy : 0.f;
    f16x2 o; o[0] = (_Float16)vx; o[1] = (_Float16)vy;
    *(f16x2*)((_Float16*)outp + (size_t)wid * 128 + 2 * lane) = o;
  } else {
    vx += __shfl_xor(vx, 16); vx += __shfl_xor(vx, 32);
    vy += __shfl_xor(vy, 16); vy += __shfl_xor(vy, 32);
    if (lane < 16) {
      float ox = vx * 0.25f + bias[2 * lane];
      float oy = vy * 0.25f + bias[2 * lane + 1];
      *(float2*)((float*)outp + (size_t)wid * 32 + 2 * lane) = make_float2(ox, oy);
    }
  }
}

extern "C" void kernel_launch(void* const* d_in, const int* in_sizes, int n_in,
                              void* d_out, int out_size, void* d_ws, size_t ws_size,
                              hipStream_t stream) {
  const float* x   = (const float*)d_in[0];
  const int*   ei  = (const int*)d_in[1];
  const float* W1  = (const float*)d_in[2];
  const float* a1s = (const float*)d_in[3];
  const float* a1d = (const float*)d_in[4];
  const float* b1  = (const float*)d_in[5];
  const float* W2  = (const float*)d_in[6];
  const float* a2s = (const float*)d_in[7];
  const float* a2d = (const float*)d_in[8];
  const float* b2  = (const float*)d_in[9];
  const float* M1w = (const float*)d_in[10];
  const float* M1b = (const float*)d_in[11];
  const float* g1  = (const float*)d_in[12];
  const float* be1 = (const float*)d_in[13];
  const float* M2w = (const float*)d_in[14];
  const float* M2b = (const float*)d_in[15];
  const float* g2  = (const float*)d_in[16];
  const float* be2 = (const float*)d_in[17];
  const float* W3  = (const float*)d_in[18];
  const float* a3s = (const float*)d_in[19];
  const float* a3d = (const float*)d_in[20];
  const float* b3  = (const float*)d_in[21];

  const int N = in_sizes[0] / 128;
  const int E = in_sizes[1] / 2;
  const int S = E + N;                 // csr slots (edges + self-loops)

  char* w = (char*)d_ws;
  _Float16* bufA = (_Float16*)w; w += (size_t)N * 128 * 2;
  _Float16* bufB = (_Float16*)w; w += (size_t)N * 128 * 2;
  _Float16* bufM = (_Float16*)w; w += (size_t)N * 64 * 2;
  float* esb  = (float*)w; w += (size_t)N * 4 * 4;
  float* edb  = (float*)w; w += (size_t)N * 4 * 4;
  int* rowptr = (int*)w;   w += (size_t)(N + 1) * 4;
  unsigned* csr = (unsigned*)w; w += (size_t)S * 4;
  float* wq   = (float*)w; w += (size_t)S * 4 * 4;
  unsigned* staging = (unsigned*)w; w += (size_t)E * 4;
  int* bucketSize = (int*)w; w += 256 * 4;
  int* edgeStart  = (int*)w; w += 257 * 4;
  int* cursor     = (int*)w; w += 256 * 4;
  int* csrStart   = (int*)w; w += 256 * 4;
  // split-fp16 transposed weights (hi/lo)
  _Float16* W1H = (_Float16*)w; w += 144 * 128 * 2;
  _Float16* W1L = (_Float16*)w; w += 144 * 128 * 2;
  _Float16* W2H = (_Float16*)w; w += 144 * 128 * 2;
  _Float16* W2L = (_Float16*)w; w += 144 * 128 * 2;
  _Float16* W3H = (_Float16*)w; w += 144 * 128 * 2;
  _Float16* W3L = (_Float16*)w; w += 144 * 128 * 2;
  _Float16* M1H = (_Float16*)w; w += 64 * 128 * 2;
  _Float16* M1L = (_Float16*)w; w += 64 * 128 * 2;
  _Float16* M2H = (_Float16*)w; w += 128 * 64 * 2;
  _Float16* M2L = (_Float16*)w; w += 128 * 64 * 2;

  const int gb = (N + 127) / 128;
  const int aggb = (N + 3) / 4;        // 4 waves per block
  const int nbk = (N + 255) / 256;     // buckets
  const int pbk = (E + PCH - 1) / PCH;
  const int wqb = (S * 4 + 255) / 256;

  // ---- weight prep (single dispatch) ----
  wprep_all<<<280, 256, 0, stream>>>(W1, a1s, a1d, W1H, W1L,
                                     W2, a2s, a2d, W2H, W2L,
                                     W3, a3s, a3d, W3H, W3L,
                                     M1w, M1H, M1L, M2w, M2H, M2L);

  // ---- CSR build: bucket radix partition ----
  zero256<<<1, 256, 0, stream>>>(bucketSize);
  eb_hist<<<256, 256, 0, stream>>>(ei, bucketSize, E);
  eb_scan<<<1, 256, 0, stream>>>(bucketSize, edgeStart, cursor, csrStart, N);
  eb_part<<<pbk, 256, 0, stream>>>(ei, cursor, staging, E);
  eb_csr<<<nbk, 256, 0, stream>>>(staging, edgeStart, csrStart, rowptr, csr, N);

  // ---- layer 0: conv0(+attn) -> wq -> agg(relu+bias) -> MLP x2 ----
  gemm_f16<144, 128, 128, 0, 1, float><<<gb, 256, 0, stream>>>(
      x, W1H, W1L, bufA, N, nullptr, nullptr, nullptr, esb, edb);
  wq_comp<<<wqb, 256, 0, stream>>>(csr, esb, edb, wq, S * 4);
  gat_agg<0><<<aggb, 256, 0, stream>>>(bufA, rowptr, csr, wq, b1, bufB, N);
  gemm_f16<64, 64, 128, 1, 0, _Float16><<<gb, 256, 0, stream>>>(
      bufB, M1H, M1L, bufM, N, M1b, g1, be1, nullptr, nullptr);
  gemm_f16<128, 128, 64, 1, 0, _Float16><<<gb, 256, 0, stream>>>(
      bufM, M2H, M2L, bufA, N, M2b, g2, be2, nullptr, nullptr);

  // ---- layer 1: conv1(+attn) -> wq -> agg(relu+bias) ----
  gemm_f16<144, 128, 128, 0, 1, _Float16><<<gb, 256, 0, stream>>>(
      bufA, W2H, W2L, bufB, N, nullptr, nullptr, nullptr, esb, edb);
  wq_comp<<<wqb, 256, 0, stream>>>(csr, esb, edb, wq, S * 4);
  gat_agg<0><<<aggb, 256, 0, stream>>>(bufB, rowptr, csr, wq, b2, bufA, N);

  // ---- layer 2: conv2(+attn) -> wq -> agg (mean heads, +b3) ----
  gemm_f16<144, 128, 128, 0, 1, _Float16><<<gb, 256, 0, stream>>>(
      bufA, W3H, W3L, bufB, N, nullptr, nullptr, nullptr, esb, edb);
  wq_comp<<<wqb, 256, 0, stream>>>(csr, esb, edb, wq, S * 4);
  gat_agg<1><<<aggb, 256, 0, stream>>>(bufB, rowptr, csr, wq, b3, d_out, N);
}

// Round 9
// 336.810 us; speedup vs baseline: 1.1368x; 1.1368x over previous
//
#include <hip/hip_runtime.h>
#include <hip/hip_bf16.h>

#define NEG_SLOPE 0.2f
#define BN_RS 0.9999950000374997f   // 1/sqrt(1 + 1e-5)

typedef __attribute__((ext_vector_type(8))) _Float16 f16x8;  // MFMA A/B frag (4 VGPR)
typedef __attribute__((ext_vector_type(2))) _Float16 f16x2;
typedef __attribute__((ext_vector_type(4))) float f32x4;     // MFMA acc

// split fp32 -> fp16 hi (RNE) + fp16 lo (RNE of residual); hi+lo carries ~22 bits
__device__ __forceinline__ void store_split(float w, _Float16* H, _Float16* L, size_t off) {
  _Float16 h = (_Float16)w;
  H[off] = h;
  L[off] = (_Float16)(w - (float)h);
}

// ---------------- CSR build: two-level bucket radix (bucket = dst>>8) ----------------
// Requires N <= 65536 (dst and src packed into 16 bits each). N = 50000 here.
// csr entry = (dst<<16) | src.

__global__ void zero256(int* p) { p[threadIdx.x] = 0; }

__global__ void eb_hist(const int* __restrict__ ei, int* __restrict__ bucketSize, int E) {
  __shared__ int h[256];
  int tid = threadIdx.x;
  h[tid] = 0;
  __syncthreads();
  for (int i = blockIdx.x * 256 + tid; i < E; i += gridDim.x * 256)
    atomicAdd(&h[ei[E + i] >> 8], 1);
  __syncthreads();
  if (h[tid]) atomicAdd(&bucketSize[tid], h[tid]);
}

__global__ void eb_scan(const int* __restrict__ bucketSize, int* __restrict__ edgeStart,
                        int* __restrict__ cursor, int* __restrict__ csrStart, int N) {
  __shared__ int sd[256];
  int tid = threadIdx.x;
  int v = bucketSize[tid];
  sd[tid] = v;
  __syncthreads();
  for (int off = 1; off < 256; off <<= 1) {
    int t = (tid >= off) ? sd[tid - off] : 0;
    __syncthreads();
    sd[tid] += t;
    __syncthreads();
  }
  int excl = sd[tid] - v;
  edgeStart[tid] = excl;
  cursor[tid] = excl;
  csrStart[tid] = excl + min(tid << 8, N);
  if (tid == 255) edgeStart[256] = sd[255];
}

#define PCH 4096
__global__ __launch_bounds__(256) void eb_part(const int* __restrict__ ei,
                                               int* __restrict__ cursor,
                                               unsigned* __restrict__ staging, int E) {
  __shared__ unsigned val[PCH];
  __shared__ unsigned char bk[PCH];
  __shared__ int cnt[256];
  __shared__ int base[256];
  int tid = threadIdx.x;
  cnt[tid] = 0;
  __syncthreads();
  int e0 = blockIdx.x * PCH;
  int n = min(PCH, E - e0);
  for (int j = tid; j < n; j += 256) {
    int s = ei[e0 + j], d = ei[E + e0 + j];
    val[j] = ((unsigned)(d & 255) << 16) | (unsigned)s;
    int b = d >> 8;
    bk[j] = (unsigned char)b;
    atomicAdd(&cnt[b], 1);
  }
  __syncthreads();
  if (cnt[tid]) base[tid] = atomicAdd(&cursor[tid], cnt[tid]);
  __syncthreads();
  for (int j = tid; j < n; j += 256) {
    int b = bk[j];
    int off = atomicSub(&cnt[b], 1) - 1;
    staging[base[b] + off] = val[j];
  }
}

__global__ __launch_bounds__(256) void eb_csr(
    const unsigned* __restrict__ staging, const int* __restrict__ edgeStart,
    const int* __restrict__ csrStart, int* __restrict__ rowptr,
    unsigned* __restrict__ csr, int N) {
  __shared__ int deg[256];
  __shared__ int sc[256];
  __shared__ int ex[256];
  int b = blockIdx.x, tid = threadIdx.x;
  int n0 = b << 8;
  int nn = min(256, N - n0);
  deg[tid] = (tid < nn) ? 1 : 0;   // self-loop
  __syncthreads();
  int s0 = edgeStart[b], s1 = edgeStart[b + 1];
  for (int j = s0 + tid; j < s1; j += 256)
    atomicAdd(&deg[staging[j] >> 16], 1);
  __syncthreads();
  int dv = deg[tid];
  sc[tid] = dv;
  __syncthreads();
  for (int off = 1; off < 256; off <<= 1) {
    int t = (tid >= off) ? sc[tid - off] : 0;
    __syncthreads();
    sc[tid] += t;
    __syncthreads();
  }
  int incl = sc[tid];
  int cbase = csrStart[b];
  ex[tid] = incl - dv;
  if (tid < nn) {
    rowptr[n0 + tid + 1] = cbase + incl;
    unsigned me = (unsigned)(n0 + tid);
    csr[cbase + incl - 1] = (me << 16) | me;   // self-loop at end of row
  }
  if (b == 0 && tid == 0) rowptr[0] = 0;
  deg[tid] = 0;                          // reuse as per-node cursor
  __syncthreads();
  for (int j = s0 + tid; j < s1; j += 256) {
    unsigned v = staging[j];
    int dl = v >> 16;
    unsigned src = v & 0xFFFF;
    int off = atomicAdd(&deg[dl], 1);
    csr[cbase + ex[dl] + off] = ((unsigned)(n0 + dl) << 16) | src;
  }
}

// ---------------- weight prep ----------------
// conv W[128][128] -> Wt hi/lo fp16 [144][128]: rows 0..127 = W^T split,
// rows 128..131 = combined attn-src cols (es = A @ ws), 132..135 attn-dst, 136..143 zero.
// M1 [128][64] -> [64][128]; M2 [64][128] -> [128][64].
__device__ __forceinline__ void wprep_conv(const float* __restrict__ W,
                                           const float* __restrict__ as_,
                                           const float* __restrict__ ad_,
                                           _Float16* __restrict__ H, _Float16* __restrict__ L,
                                           int lb, int tid) {
  if (lb < 64) {                       // transpose region
    int idx = lb * 256 + tid;
    int k = idx >> 7, p = idx & 127;
    store_split(W[k * 128 + p], H, L, (size_t)p * 128 + k);
  } else if (lb < 68) {                // attn-combined rows
    int idx = (lb - 64) * 256 + tid;   // 1024 entries: 8 rows x 128 k
    int rl = idx >> 7, k = idx & 127;
    const float* a = (rl < 4) ? as_ : ad_;
    int h = rl & 3;
    float s = 0.f;
#pragma unroll
    for (int f = 0; f < 32; f++) s += W[k * 128 + h * 32 + f] * a[h * 32 + f];
    store_split(s, H, L, (size_t)(128 + rl) * 128 + k);
  } else {                             // zero pad rows 136..143
    int idx = (lb - 68) * 256 + tid;
    int rl = idx >> 7, k = idx & 127;
    H[(size_t)(136 + rl) * 128 + k] = (_Float16)0.f;
    L[(size_t)(136 + rl) * 128 + k] = (_Float16)0.f;
  }
}

__global__ void wprep_all(
    const float* __restrict__ W1, const float* __restrict__ a1s, const float* __restrict__ a1d,
    _Float16* __restrict__ W1H, _Float16* __restrict__ W1L,
    const float* __restrict__ W2, const float* __restrict__ a2s, const float* __restrict__ a2d,
    _Float16* __restrict__ W2H, _Float16* __restrict__ W2L,
    const float* __restrict__ W3, const float* __restrict__ a3s, const float* __restrict__ a3d,
    _Float16* __restrict__ W3H, _Float16* __restrict__ W3L,
    const float* __restrict__ M1, _Float16* __restrict__ M1H, _Float16* __restrict__ M1L,
    const float* __restrict__ M2, _Float16* __restrict__ M2H, _Float16* __restrict__ M2L) {
  int b = blockIdx.x, tid = threadIdx.x;
  if (b < 72)       wprep_conv(W1, a1s, a1d, W1H, W1L, b, tid);
  else if (b < 144) wprep_conv(W2, a2s, a2d, W2H, W2L, b - 72, tid);
  else if (b < 216) wprep_conv(W3, a3s, a3d, W3H, W3L, b - 144, tid);
  else if (b < 248) {                  // M1: [128][64] -> [64][128]
    int idx = (b - 216) * 256 + tid;
    int k = idx >> 6, p = idx & 63;
    store_split(M1[k * 64 + p], M1H, M1L, (size_t)p * 128 + k);
  } else {                             // M2: [64][128] -> [128][64]
    int idx = (b - 248) * 256 + tid;
    int k = idx >> 7, p = idx & 127;
    store_split(M2[k * 128 + p], M2H, M2L, (size_t)p * 64 + k);
  }
}

// ---------------- conv GEMM via fp16 MFMA, W split hi/lo, attn fused ----------------
// C[N x 128](fp16) = A[N x 128] @ W; plus extra 16-wide tile -> es/ed fp32.
template <typename TA>
__global__ __launch_bounds__(256) void gemm_f16(
    const TA* __restrict__ A, const _Float16* __restrict__ WtH,
    const _Float16* __restrict__ WtL, _Float16* __restrict__ C, int N,
    float* __restrict__ esb, float* __restrict__ edb) {
  constexpr int PT = 144, PST = 128, K = 128;
  constexpr int CTB = 2;              // base col-tiles per wave (8 of 9)
  constexpr int KT = K / 32;
  __shared__ _Float16 As[128 * 32];
  __shared__ _Float16 WsH[PT * 32];
  __shared__ _Float16 WsL[PT * 32];
  const int tid = threadIdx.x;
  const int wave = tid >> 6, lane = tid & 63;
  const int quad = lane >> 4, l16 = lane & 15;
  const int row0 = blockIdx.x * 128;
  const bool xw = (wave == 0);

  f32x4 acc[8][CTB + 1];
#pragma unroll
  for (int rt = 0; rt < 8; rt++)
#pragma unroll
    for (int nt = 0; nt < CTB + 1; nt++) acc[rt][nt] = (f32x4){0.f, 0.f, 0.f, 0.f};

  for (int kc = 0; kc < KT; ++kc) {
    // ---- stage A: 128 rows x 32 halves ----
    {
      int r = tid >> 1, part = tid & 1;
      int gr = row0 + r;
      _Float16* dst = &As[r * 32 + part * 16];
      if (gr < N) {
        const TA* src = A + (size_t)gr * K + kc * 32 + part * 16;
        if constexpr (sizeof(TA) == 4) {     // fp32 input (layer 0): cvt
          f16x8 h0, h1;
#pragma unroll
          for (int j = 0; j < 8; j++) { h0[j] = (_Float16)src[j]; h1[j] = (_Float16)src[8 + j]; }
          *(f16x8*)dst = h0; *(f16x8*)(dst + 8) = h1;
        } else {                              // fp16: raw copy
          uint4 v0 = *(const uint4*)src;
          uint4 v1 = *(const uint4*)(src + 8);
          *(uint4*)dst = v0; *(uint4*)(dst + 8) = v1;
        }
      } else {
        *(uint4*)dst = make_uint4(0, 0, 0, 0);
        *(uint4*)(dst + 8) = make_uint4(0, 0, 0, 0);
      }
    }
    // ---- stage W hi/lo: PT rows x 32 halves each ----
    for (int idx = tid; idx < PT * 2; idx += 256) {
      int isL = idx >= PT;
      int p = isL ? idx - PT : idx;
      const _Float16* src = (isL ? WtL : WtH) + (size_t)p * K + kc * 32;
      _Float16* dst = (isL ? WsL : WsH) + p * 32;
      uint4 a0 = *(const uint4*)src;       uint4 a1 = *(const uint4*)(src + 8);
      uint4 a2 = *(const uint4*)(src + 16); uint4 a3 = *(const uint4*)(src + 24);
      *(uint4*)dst = a0; *(uint4*)(dst + 8) = a1;
      *(uint4*)(dst + 16) = a2; *(uint4*)(dst + 24) = a3;
    }
    __syncthreads();

    f16x8 bh[CTB], bl[CTB], bhE, blE;
#pragma unroll
    for (int nt = 0; nt < CTB; nt++) {
      int p = (wave * CTB + nt) * 16 + l16;
      bh[nt] = *(f16x8*)&WsH[p * 32 + quad * 8];
      bl[nt] = *(f16x8*)&WsL[p * 32 + quad * 8];
    }
    if (xw) {
      int p = 4 * CTB * 16 + l16;
      bhE = *(f16x8*)&WsH[p * 32 + quad * 8];
      blE = *(f16x8*)&WsL[p * 32 + quad * 8];
    }
#pragma unroll
    for (int rt = 0; rt < 8; rt++) {
      f16x8 a = *(f16x8*)&As[(rt * 16 + l16) * 32 + quad * 8];
#pragma unroll
      for (int nt = 0; nt < CTB; nt++) {
        acc[rt][nt] = __builtin_amdgcn_mfma_f32_16x16x32_f16(a, bh[nt], acc[rt][nt], 0, 0, 0);
        acc[rt][nt] = __builtin_amdgcn_mfma_f32_16x16x32_f16(a, bl[nt], acc[rt][nt], 0, 0, 0);
      }
      if (xw) {
        acc[rt][CTB] = __builtin_amdgcn_mfma_f32_16x16x32_f16(a, bhE, acc[rt][CTB], 0, 0, 0);
        acc[rt][CTB] = __builtin_amdgcn_mfma_f32_16x16x32_f16(a, blE, acc[rt][CTB], 0, 0, 0);
      }
    }
    __syncthreads();
  }

  // ---- epilogue (C/D layout: col=lane&15, row=quad*4+reg) ----
#pragma unroll
  for (int nt = 0; nt < CTB; nt++) {
    int c = (wave * CTB + nt) * 16 + l16;
#pragma unroll
    for (int rt = 0; rt < 8; rt++)
#pragma unroll
      for (int g = 0; g < 4; g++) {
        int r = row0 + rt * 16 + quad * 4 + g;
        if (r < N) C[(size_t)r * PST + c] = (_Float16)acc[rt][nt][g];
      }
  }
  if (wave == 0 && l16 < 8) {
    float* dstb = (l16 < 4) ? esb : edb;
    int h = l16 & 3;
#pragma unroll
    for (int rt = 0; rt < 8; rt++)
#pragma unroll
      for (int g = 0; g < 4; g++) {
        int r = row0 + rt * 16 + quad * 4 + g;
        if (r < N) dstb[(size_t)r * 4 + h] = acc[rt][CTB][g];
      }
  }
}

// ---------------- fused MLP: out = bn2(relu(bn1(relu(A@M1+b1))@M2+b2)) ----------------
// A [N,128] fp16 -> T [128,64] in LDS -> out [N,128] fp16.
__global__ __launch_bounds__(256) void mlp_fused(
    const _Float16* __restrict__ A,
    const _Float16* __restrict__ M1H, const _Float16* __restrict__ M1L,
    const _Float16* __restrict__ M2H, const _Float16* __restrict__ M2L,
    _Float16* __restrict__ C, int N,
    const float* __restrict__ b1v, const float* __restrict__ g1v, const float* __restrict__ be1v,
    const float* __restrict__ b2v, const float* __restrict__ g2v, const float* __restrict__ be2v) {
  __shared__ _Float16 As[128 * 32];
  __shared__ _Float16 W1Hs[64 * 32], W1Ls[64 * 32];
  __shared__ _Float16 T[128 * 72];          // +8 pad halves per row
  __shared__ _Float16 W2Hs[128 * 32], W2Ls[128 * 32];
  const int tid = threadIdx.x;
  const int wave = tid >> 6, lane = tid & 63;
  const int quad = lane >> 4, l16 = lane & 15;
  const int row0 = blockIdx.x * 128;

  // ---- GEMM 1: [128x128] @ [128x64] ----
  f32x4 acc1[8];
#pragma unroll
  for (int rt = 0; rt < 8; rt++) acc1[rt] = (f32x4){0.f, 0.f, 0.f, 0.f};
  for (int kc = 0; kc < 4; ++kc) {
    {
      int r = tid >> 1, part = tid & 1;
      int gr = row0 + r;
      _Float16* dst = &As[r * 32 + part * 16];
      if (gr < N) {
        const _Float16* src = A + (size_t)gr * 128 + kc * 32 + part * 16;
        uint4 v0 = *(const uint4*)src;
        uint4 v1 = *(const uint4*)(src + 8);
        *(uint4*)dst = v0; *(uint4*)(dst + 8) = v1;
      } else {
        *(uint4*)dst = make_uint4(0, 0, 0, 0);
        *(uint4*)(dst + 8) = make_uint4(0, 0, 0, 0);
      }
    }
    if (tid < 128) {
      int isL = tid >= 64;
      int p = tid & 63;
      const _Float16* src = (isL ? M1L : M1H) + (size_t)p * 128 + kc * 32;
      _Float16* dst = (isL ? W1Ls : W1Hs) + p * 32;
      uint4 a0 = *(const uint4*)src;       uint4 a1 = *(const uint4*)(src + 8);
      uint4 a2 = *(const uint4*)(src + 16); uint4 a3 = *(const uint4*)(src + 24);
      *(uint4*)dst = a0; *(uint4*)(dst + 8) = a1;
      *(uint4*)(dst + 16) = a2; *(uint4*)(dst + 24) = a3;
    }
    __syncthreads();
    int p = wave * 16 + l16;
    f16x8 bh = *(f16x8*)&W1Hs[p * 32 + quad * 8];
    f16x8 bl = *(f16x8*)&W1Ls[p * 32 + quad * 8];
#pragma unroll
    for (int rt = 0; rt < 8; rt++) {
      f16x8 a = *(f16x8*)&As[(rt * 16 + l16) * 32 + quad * 8];
      acc1[rt] = __builtin_amdgcn_mfma_f32_16x16x32_f16(a, bh, acc1[rt], 0, 0, 0);
      acc1[rt] = __builtin_amdgcn_mfma_f32_16x16x32_f16(a, bl, acc1[rt], 0, 0, 0);
    }
    __syncthreads();
  }
  // epilogue 1 -> T (LDS)
  {
    int c = wave * 16 + l16;
    float bi = b1v[c], ga = g1v[c] * BN_RS, be = be1v[c];
#pragma unroll
    for (int rt = 0; rt < 8; rt++)
#pragma unroll
      for (int g = 0; g < 4; g++) {
        int r = rt * 16 + quad * 4 + g;
        float v = acc1[rt][g] + bi;
        v = v > 0.f ? v : 0.f;
        v = v * ga + be;
        T[r * 72 + c] = (_Float16)v;
      }
  }
  __syncthreads();

  // ---- GEMM 2: T[128x64] @ [64x128] ----
  f32x4 acc2[8][2];
#pragma unroll
  for (int rt = 0; rt < 8; rt++)
#pragma unroll
    for (int nt = 0; nt < 2; nt++) acc2[rt][nt] = (f32x4){0.f, 0.f, 0.f, 0.f};
  for (int kc = 0; kc < 2; ++kc) {
    {
      int isL = tid >= 128;
      int p = tid & 127;
      const _Float16* src = (isL ? M2L : M2H) + (size_t)p * 64 + kc * 32;
      _Float16* dst = (isL ? W2Ls : W2Hs) + p * 32;
      uint4 a0 = *(const uint4*)src;       uint4 a1 = *(const uint4*)(src + 8);
      uint4 a2 = *(const uint4*)(src + 16); uint4 a3 = *(const uint4*)(src + 24);
      *(uint4*)dst = a0; *(uint4*)(dst + 8) = a1;
      *(uint4*)(dst + 16) = a2; *(uint4*)(dst + 24) = a3;
    }
    __syncthreads();
    f16x8 bh[2], bl[2];
#pragma unroll
    for (int nt = 0; nt < 2; nt++) {
      int p = (wave * 2 + nt) * 16 + l16;
      bh[nt] = *(f16x8*)&W2Hs[p * 32 + quad * 8];
      bl[nt] = *(f16x8*)&W2Ls[p * 32 + quad * 8];
    }
#pragma unroll
    for (int rt = 0; rt < 8; rt++) {
      f16x8 a = *(f16x8*)&T[(rt * 16 + l16) * 72 + kc * 32 + quad * 8];
#pragma unroll
      for (int nt = 0; nt < 2; nt++) {
        acc2[rt][nt] = __builtin_amdgcn_mfma_f32_16x16x32_f16(a, bh[nt], acc2[rt][nt], 0, 0, 0);
        acc2[rt][nt] = __builtin_amdgcn_mfma_f32_16x16x32_f16(a, bl[nt], acc2[rt][nt], 0, 0, 0);
      }
    }
    __syncthreads();
  }
  // epilogue 2 -> C
#pragma unroll
  for (int nt = 0; nt < 2; nt++) {
    int c = (wave * 2 + nt) * 16 + l16;
    float bi = b2v[c], ga = g2v[c] * BN_RS, be = be2v[c];
#pragma unroll
    for (int rt = 0; rt < 8; rt++)
#pragma unroll
      for (int g = 0; g < 4; g++) {
        int r = row0 + rt * 16 + quad * 4 + g;
        if (r < N) {
          float v = acc2[rt][nt][g] + bi;
          v = v > 0.f ? v : 0.f;
          v = v * ga + be;
          C[(size_t)r * 128 + c] = (_Float16)v;
        }
      }
  }
}

// ---------------- GAT aggregation: one wave per dst node, fused weights ----------------
// Per 16-edge chunk: lane (slot=lane>>2, head=lane&3) computes exp(leaky(es+ed)) ONCE
// into LDS (double-buffered, prefetched one chunk ahead); src idx cached in LDS.
// Phase 2: depth-1 8-wide hv gathers. Intra-wave LDS ordering -> no barriers.
// MODE 0: out fp16 [N,128] = relu(S/z + bias). MODE 1: out fp32 [N,32] = mean_heads + bias.
template <int MODE>
__global__ __launch_bounds__(256) void gat_agg(
    const _Float16* __restrict__ hx, const int* __restrict__ rowptr,
    const unsigned* __restrict__ csr, const float* __restrict__ es,
    const float* __restrict__ ed, const float* __restrict__ bias,
    void* __restrict__ outp, int N) {
  __shared__ float wbuf[4][2][16][4];
  __shared__ int sbuf[4][2][16];
  int wid = __builtin_amdgcn_readfirstlane((int)((blockIdx.x * 256 + threadIdx.x) >> 6));
  if (wid >= N) return;
  int wave = threadIdx.x >> 6;
  int lane = threadIdx.x & 63;
  int head = lane >> 4;
  int j4 = lane >> 2, h4 = lane & 3;
  int beg = rowptr[wid], end = rowptr[wid + 1];
  float edv4 = ed[wid * 4 + h4];
  float ax = 0.f, ay = 0.f, z = 0.f;
  const _Float16* hb = hx + 2 * lane;
  int nch = (end - beg + 15) >> 4;

  // prologue: weights for chunk 0
  {
    int m = end - beg; if (m > 16) m = 16;
    if (j4 < m) {
      int s = (int)(csr[beg + j4] & 0xFFFFu);
      float t = es[s * 4 + h4] + edv4;
      t = t > 0.f ? t : NEG_SLOPE * t;
      wbuf[wave][0][j4][h4] = __expf(t);
      if (h4 == 0) sbuf[wave][0][j4] = s;
    }
  }
  int pb = 0;
  for (int ci = 0; ci < nch; ++ci) {
    int c = beg + (ci << 4);
    int m = end - c; if (m > 16) m = 16;
    if (ci + 1 < nch) {     // prefetch next chunk's weights into other buffer
      int c2 = c + 16;
      int m2 = end - c2; if (m2 > 16) m2 = 16;
      if (j4 < m2) {
        int s = (int)(csr[c2 + j4] & 0xFFFFu);
        float t = es[s * 4 + h4] + edv4;
        t = t > 0.f ? t : NEG_SLOPE * t;
        wbuf[wave][pb ^ 1][j4][h4] = __expf(t);
        if (h4 == 0) sbuf[wave][pb ^ 1][j4] = s;
      }
    }
    int j = 0;
    for (; j + 8 <= m; j += 8) {
      int s0 = sbuf[wave][pb][j + 0], s1 = sbuf[wave][pb][j + 1];
      int s2 = sbuf[wave][pb][j + 2], s3 = sbuf[wave][pb][j + 3];
      int s4 = sbuf[wave][pb][j + 4], s5 = sbuf[wave][pb][j + 5];
      int s6 = sbuf[wave][pb][j + 6], s7 = sbuf[wave][pb][j + 7];
      float w0 = wbuf[wave][pb][j + 0][head], w1 = wbuf[wave][pb][j + 1][head];
      float w2 = wbuf[wave][pb][j + 2][head], w3 = wbuf[wave][pb][j + 3][head];
      float w4 = wbuf[wave][pb][j + 4][head], w5 = wbuf[wave][pb][j + 5][head];
      float w6 = wbuf[wave][pb][j + 6][head], w7 = wbuf[wave][pb][j + 7][head];
      f16x2 h0 = *(const f16x2*)(hb + (size_t)s0 * 128);
      f16x2 h1 = *(const f16x2*)(hb + (size_t)s1 * 128);
      f16x2 h2 = *(const f16x2*)(hb + (size_t)s2 * 128);
      f16x2 h3 = *(const f16x2*)(hb + (size_t)s3 * 128);
      f16x2 h4v = *(const f16x2*)(hb + (size_t)s4 * 128);
      f16x2 h5 = *(const f16x2*)(hb + (size_t)s5 * 128);
      f16x2 h6 = *(const f16x2*)(hb + (size_t)s6 * 128);
      f16x2 h7 = *(const f16x2*)(hb + (size_t)s7 * 128);
      z += ((w0 + w1) + (w2 + w3)) + ((w4 + w5) + (w6 + w7));
      ax = fmaf(w0, (float)h0[0], ax); ay = fmaf(w0, (float)h0[1], ay);
      ax = fmaf(w1, (float)h1[0], ax); ay = fmaf(w1, (float)h1[1], ay);
      ax = fmaf(w2, (float)h2[0], ax); ay = fmaf(w2, (float)h2[1], ay);
      ax = fmaf(w3, (float)h3[0], ax); ay = fmaf(w3, (float)h3[1], ay);
      ax = fmaf(w4, (float)h4v[0], ax); ay = fmaf(w4, (float)h4v[1], ay);
      ax = fmaf(w5, (float)h5[0], ax); ay = fmaf(w5, (float)h5[1], ay);
      ax = fmaf(w6, (float)h6[0], ax); ay = fmaf(w6, (float)h6[1], ay);
      ax = fmaf(w7, (float)h7[0], ax); ay = fmaf(w7, (float)h7[1], ay);
    }
    for (; j < m; ++j) {
      int s = sbuf[wave][pb][j];
      float w = wbuf[wave][pb][j][head];
      f16x2 hv = *(const f16x2*)(hb + (size_t)s * 128);
      z += w;
      ax = fmaf(w, (float)hv[0], ax);
      ay = fmaf(w, (float)hv[1], ay);
    }
    pb ^= 1;
  }
  float inv = 1.f / (z + 1e-16f);
  float vx = ax * inv, vy = ay * inv;
  if (MODE == 0) {
    vx += bias[2 * lane]; vy += bias[2 * lane + 1];
    vx = vx > 0.f ? vx : 0.f;  vy = vy > 0.f ? vy : 0.f;
    f16x2 o; o[0] = (_Float16)vx; o[1] = (_Float16)vy;
    *(f16x2*)((_Float16*)outp + (size_t)wid * 128 + 2 * lane) = o;
  } else {
    vx += __shfl_xor(vx, 16); vx += __shfl_xor(vx, 32);
    vy += __shfl_xor(vy, 16); vy += __shfl_xor(vy, 32);
    if (lane < 16) {
      float ox = vx * 0.25f + bias[2 * lane];
      float oy = vy * 0.25f + bias[2 * lane + 1];
      *(float2*)((float*)outp + (size_t)wid * 32 + 2 * lane) = make_float2(ox, oy);
    }
  }
}

extern "C" void kernel_launch(void* const* d_in, const int* in_sizes, int n_in,
                              void* d_out, int out_size, void* d_ws, size_t ws_size,
                              hipStream_t stream) {
  const float* x   = (const float*)d_in[0];
  const int*   ei  = (const int*)d_in[1];
  const float* W1  = (const float*)d_in[2];
  const float* a1s = (const float*)d_in[3];
  const float* a1d = (const float*)d_in[4];
  const float* b1  = (const float*)d_in[5];
  const float* W2  = (const float*)d_in[6];
  const float* a2s = (const float*)d_in[7];
  const float* a2d = (const float*)d_in[8];
  const float* b2  = (const float*)d_in[9];
  const float* M1w = (const float*)d_in[10];
  const float* M1b = (const float*)d_in[11];
  const float* g1  = (const float*)d_in[12];
  const float* be1 = (const float*)d_in[13];
  const float* M2w = (const float*)d_in[14];
  const float* M2b = (const float*)d_in[15];
  const float* g2  = (const float*)d_in[16];
  const float* be2 = (const float*)d_in[17];
  const float* W3  = (const float*)d_in[18];
  const float* a3s = (const float*)d_in[19];
  const float* a3d = (const float*)d_in[20];
  const float* b3  = (const float*)d_in[21];

  const int N = in_sizes[0] / 128;
  const int E = in_sizes[1] / 2;
  const int S = E + N;                 // csr slots (edges + self-loops)

  char* w = (char*)d_ws;
  _Float16* bufA = (_Float16*)w; w += (size_t)N * 128 * 2;
  _Float16* bufB = (_Float16*)w; w += (size_t)N * 128 * 2;
  float* esb  = (float*)w; w += (size_t)N * 4 * 4;
  float* edb  = (float*)w; w += (size_t)N * 4 * 4;
  int* rowptr = (int*)w;   w += (size_t)(N + 1) * 4;
  unsigned* csr = (unsigned*)w; w += (size_t)S * 4;
  unsigned* staging = (unsigned*)w; w += (size_t)E * 4;
  int* bucketSize = (int*)w; w += 256 * 4;
  int* edgeStart  = (int*)w; w += 257 * 4;
  int* cursor     = (int*)w; w += 256 * 4;
  int* csrStart   = (int*)w; w += 256 * 4;
  // split-fp16 transposed weights (hi/lo)
  _Float16* W1H = (_Float16*)w; w += 144 * 128 * 2;
  _Float16* W1L = (_Float16*)w; w += 144 * 128 * 2;
  _Float16* W2H = (_Float16*)w; w += 144 * 128 * 2;
  _Float16* W2L = (_Float16*)w; w += 144 * 128 * 2;
  _Float16* W3H = (_Float16*)w; w += 144 * 128 * 2;
  _Float16* W3L = (_Float16*)w; w += 144 * 128 * 2;
  _Float16* M1H = (_Float16*)w; w += 64 * 128 * 2;
  _Float16* M1L = (_Float16*)w; w += 64 * 128 * 2;
  _Float16* M2H = (_Float16*)w; w += 128 * 64 * 2;
  _Float16* M2L = (_Float16*)w; w += 128 * 64 * 2;

  const int gb = (N + 127) / 128;
  const int aggb = (N + 3) / 4;        // 4 waves per block
  const int nbk = (N + 255) / 256;     // buckets
  const int pbk = (E + PCH - 1) / PCH;

  // ---- weight prep (single dispatch) ----
  wprep_all<<<280, 256, 0, stream>>>(W1, a1s, a1d, W1H, W1L,
                                     W2, a2s, a2d, W2H, W2L,
                                     W3, a3s, a3d, W3H, W3L,
                                     M1w, M1H, M1L, M2w, M2H, M2L);

  // ---- CSR build: bucket radix partition ----
  zero256<<<1, 256, 0, stream>>>(bucketSize);
  eb_hist<<<256, 256, 0, stream>>>(ei, bucketSize, E);
  eb_scan<<<1, 256, 0, stream>>>(bucketSize, edgeStart, cursor, csrStart, N);
  eb_part<<<pbk, 256, 0, stream>>>(ei, cursor, staging, E);
  eb_csr<<<nbk, 256, 0, stream>>>(staging, edgeStart, csrStart, rowptr, csr, N);

  // ---- layer 0: conv0(+attn) -> agg(relu+bias) -> fused MLP ----
  gemm_f16<float><<<gb, 256, 0, stream>>>(x, W1H, W1L, bufA, N, esb, edb);
  gat_agg<0><<<aggb, 256, 0, stream>>>(bufA, rowptr, csr, esb, edb, b1, bufB, N);
  mlp_fused<<<gb, 256, 0, stream>>>(bufB, M1H, M1L, M2H, M2L, bufA, N,
                                    M1b, g1, be1, M2b, g2, be2);

  // ---- layer 1: conv1(+attn) -> agg(relu+bias) ----
  gemm_f16<_Float16><<<gb, 256, 0, stream>>>(bufA, W2H, W2L, bufB, N, esb, edb);
  gat_agg<0><<<aggb, 256, 0, stream>>>(bufB, rowptr, csr, esb, edb, b2, bufA, N);

  // ---- layer 2: conv2(+attn) -> agg (mean heads, +b3) ----
  gemm_f16<_Float16><<<gb, 256, 0, stream>>>(bufA, W3H, W3L, bufB, N, esb, edb);
  gat_agg<1><<<aggb, 256, 0, stream>>>(bufB, rowptr, csr, esb, edb, b3, d_out, N);
}

// Round 10
// 322.317 us; speedup vs baseline: 1.1879x; 1.0450x over previous
//
#include <hip/hip_runtime.h>
#include <hip/hip_bf16.h>

#define NEG_SLOPE 0.2f
#define BN_RS 0.9999950000374997f   // 1/sqrt(1 + 1e-5)

typedef __attribute__((ext_vector_type(8))) _Float16 f16x8;  // MFMA A/B frag (4 VGPR)
typedef __attribute__((ext_vector_type(2))) _Float16 f16x2;
typedef __attribute__((ext_vector_type(4))) float f32x4;     // MFMA acc

// split fp32 -> fp16 hi (RNE) + fp16 lo (RNE of residual); hi+lo carries ~22 bits
__device__ __forceinline__ void store_split(float w, _Float16* H, _Float16* L, size_t off) {
  _Float16 h = (_Float16)w;
  H[off] = h;
  L[off] = (_Float16)(w - (float)h);
}

// ---------------- CSR build: two-level bucket radix (bucket = dst>>8) ----------------
// Requires N <= 65536 (dst and src packed into 16 bits each). N = 50000 here.
// csr entry = (dst<<16) | src.

__global__ void eb_hist(const int* __restrict__ ei, int* __restrict__ bucketSize, int E) {
  __shared__ int h[256];
  int tid = threadIdx.x;
  h[tid] = 0;
  __syncthreads();
  for (int i = blockIdx.x * 256 + tid; i < E; i += gridDim.x * 256)
    atomicAdd(&h[ei[E + i] >> 8], 1);
  __syncthreads();
  if (h[tid]) atomicAdd(&bucketSize[tid], h[tid]);
}

__global__ void eb_scan(const int* __restrict__ bucketSize, int* __restrict__ edgeStart,
                        int* __restrict__ cursor, int* __restrict__ csrStart, int N) {
  __shared__ int sd[256];
  int tid = threadIdx.x;
  int v = bucketSize[tid];
  sd[tid] = v;
  __syncthreads();
  for (int off = 1; off < 256; off <<= 1) {
    int t = (tid >= off) ? sd[tid - off] : 0;
    __syncthreads();
    sd[tid] += t;
    __syncthreads();
  }
  int excl = sd[tid] - v;
  edgeStart[tid] = excl;
  cursor[tid] = excl;
  csrStart[tid] = excl + min(tid << 8, N);
  if (tid == 255) edgeStart[256] = sd[255];
}

#define PCH 4096
__global__ __launch_bounds__(256) void eb_part(const int* __restrict__ ei,
                                               int* __restrict__ cursor,
                                               unsigned* __restrict__ staging, int E) {
  __shared__ unsigned val[PCH];
  __shared__ unsigned char bk[PCH];
  __shared__ int cnt[256];
  __shared__ int base[256];
  int tid = threadIdx.x;
  cnt[tid] = 0;
  __syncthreads();
  int e0 = blockIdx.x * PCH;
  int n = min(PCH, E - e0);
  for (int j = tid; j < n; j += 256) {
    int s = ei[e0 + j], d = ei[E + e0 + j];
    val[j] = ((unsigned)(d & 255) << 16) | (unsigned)s;
    int b = d >> 8;
    bk[j] = (unsigned char)b;
    atomicAdd(&cnt[b], 1);
  }
  __syncthreads();
  if (cnt[tid]) base[tid] = atomicAdd(&cursor[tid], cnt[tid]);
  __syncthreads();
  for (int j = tid; j < n; j += 256) {
    int b = bk[j];
    int off = atomicSub(&cnt[b], 1) - 1;
    staging[base[b] + off] = val[j];
  }
}

__global__ __launch_bounds__(256) void eb_csr(
    const unsigned* __restrict__ staging, const int* __restrict__ edgeStart,
    const int* __restrict__ csrStart, int* __restrict__ rowptr,
    unsigned* __restrict__ csr, int N) {
  __shared__ int deg[256];
  __shared__ int sc[256];
  __shared__ int ex[256];
  int b = blockIdx.x, tid = threadIdx.x;
  int n0 = b << 8;
  int nn = min(256, N - n0);
  deg[tid] = (tid < nn) ? 1 : 0;   // self-loop
  __syncthreads();
  int s0 = edgeStart[b], s1 = edgeStart[b + 1];
  for (int j = s0 + tid; j < s1; j += 256)
    atomicAdd(&deg[staging[j] >> 16], 1);
  __syncthreads();
  int dv = deg[tid];
  sc[tid] = dv;
  __syncthreads();
  for (int off = 1; off < 256; off <<= 1) {
    int t = (tid >= off) ? sc[tid - off] : 0;
    __syncthreads();
    sc[tid] += t;
    __syncthreads();
  }
  int incl = sc[tid];
  int cbase = csrStart[b];
  ex[tid] = incl - dv;
  if (tid < nn) {
    rowptr[n0 + tid + 1] = cbase + incl;
    unsigned me = (unsigned)(n0 + tid);
    csr[cbase + incl - 1] = (me << 16) | me;   // self-loop at end of row
  }
  if (b == 0 && tid == 0) rowptr[0] = 0;
  deg[tid] = 0;                          // reuse as per-node cursor
  __syncthreads();
  for (int j = s0 + tid; j < s1; j += 256) {
    unsigned v = staging[j];
    int dl = v >> 16;
    unsigned src = v & 0xFFFF;
    int off = atomicAdd(&deg[dl], 1);
    csr[cbase + ex[dl] + off] = ((unsigned)(n0 + dl) << 16) | src;
  }
}

// ---------------- weight prep ----------------
// conv W[128][128] -> Wt hi/lo fp16 [144][128]: rows 0..127 = W^T split,
// rows 128..131 = combined attn-src cols (es = A @ ws), 132..135 attn-dst, 136..143 zero.
// M1 [128][64] -> [64][128]; M2 [64][128] -> [128][64]. Block 280 zeroes bucketSize.
__device__ __forceinline__ void wprep_conv(const float* __restrict__ W,
                                           const float* __restrict__ as_,
                                           const float* __restrict__ ad_,
                                           _Float16* __restrict__ H, _Float16* __restrict__ L,
                                           int lb, int tid) {
  if (lb < 64) {                       // transpose region
    int idx = lb * 256 + tid;
    int k = idx >> 7, p = idx & 127;
    store_split(W[k * 128 + p], H, L, (size_t)p * 128 + k);
  } else if (lb < 68) {                // attn-combined rows
    int idx = (lb - 64) * 256 + tid;   // 1024 entries: 8 rows x 128 k
    int rl = idx >> 7, k = idx & 127;
    const float* a = (rl < 4) ? as_ : ad_;
    int h = rl & 3;
    float s = 0.f;
#pragma unroll
    for (int f = 0; f < 32; f++) s += W[k * 128 + h * 32 + f] * a[h * 32 + f];
    store_split(s, H, L, (size_t)(128 + rl) * 128 + k);
  } else {                             // zero pad rows 136..143
    int idx = (lb - 68) * 256 + tid;
    int rl = idx >> 7, k = idx & 127;
    H[(size_t)(136 + rl) * 128 + k] = (_Float16)0.f;
    L[(size_t)(136 + rl) * 128 + k] = (_Float16)0.f;
  }
}

__global__ void wprep_all(
    const float* __restrict__ W1, const float* __restrict__ a1s, const float* __restrict__ a1d,
    _Float16* __restrict__ W1H, _Float16* __restrict__ W1L,
    const float* __restrict__ W2, const float* __restrict__ a2s, const float* __restrict__ a2d,
    _Float16* __restrict__ W2H, _Float16* __restrict__ W2L,
    const float* __restrict__ W3, const float* __restrict__ a3s, const float* __restrict__ a3d,
    _Float16* __restrict__ W3H, _Float16* __restrict__ W3L,
    const float* __restrict__ M1, _Float16* __restrict__ M1H, _Float16* __restrict__ M1L,
    const float* __restrict__ M2, _Float16* __restrict__ M2H, _Float16* __restrict__ M2L,
    int* __restrict__ bucketSize) {
  int b = blockIdx.x, tid = threadIdx.x;
  if (b < 72)       wprep_conv(W1, a1s, a1d, W1H, W1L, b, tid);
  else if (b < 144) wprep_conv(W2, a2s, a2d, W2H, W2L, b - 72, tid);
  else if (b < 216) wprep_conv(W3, a3s, a3d, W3H, W3L, b - 144, tid);
  else if (b < 248) {                  // M1: [128][64] -> [64][128]
    int idx = (b - 216) * 256 + tid;
    int k = idx >> 6, p = idx & 63;
    store_split(M1[k * 64 + p], M1H, M1L, (size_t)p * 128 + k);
  } else if (b < 280) {                // M2: [64][128] -> [128][64]
    int idx = (b - 248) * 256 + tid;
    int k = idx >> 7, p = idx & 127;
    store_split(M2[k * 128 + p], M2H, M2L, (size_t)p * 64 + k);
  } else {                             // zero bucketSize
    bucketSize[tid] = 0;
  }
}

// ---------------- conv GEMM via fp16 MFMA, W split hi/lo, attn fused ----------------
// C[N x 128](fp16) = A[N x 128] @ W; plus extra 16-wide tile -> es/ed fp32.
template <typename TA>
__global__ __launch_bounds__(256) void gemm_f16(
    const TA* __restrict__ A, const _Float16* __restrict__ WtH,
    const _Float16* __restrict__ WtL, _Float16* __restrict__ C, int N,
    float* __restrict__ esb, float* __restrict__ edb) {
  constexpr int PT = 144, PST = 128, K = 128;
  constexpr int CTB = 2;              // base col-tiles per wave (8 of 9)
  constexpr int KT = K / 32;
  __shared__ _Float16 As[128 * 32];
  __shared__ _Float16 WsH[PT * 32];
  __shared__ _Float16 WsL[PT * 32];
  const int tid = threadIdx.x;
  const int wave = tid >> 6, lane = tid & 63;
  const int quad = lane >> 4, l16 = lane & 15;
  const int row0 = blockIdx.x * 128;
  const bool xw = (wave == 0);

  f32x4 acc[8][CTB + 1];
#pragma unroll
  for (int rt = 0; rt < 8; rt++)
#pragma unroll
    for (int nt = 0; nt < CTB + 1; nt++) acc[rt][nt] = (f32x4){0.f, 0.f, 0.f, 0.f};

  for (int kc = 0; kc < KT; ++kc) {
    // ---- stage A: 128 rows x 32 halves ----
    {
      int r = tid >> 1, part = tid & 1;
      int gr = row0 + r;
      _Float16* dst = &As[r * 32 + part * 16];
      if (gr < N) {
        const TA* src = A + (size_t)gr * K + kc * 32 + part * 16;
        if constexpr (sizeof(TA) == 4) {     // fp32 input (layer 0): cvt
          f16x8 h0, h1;
#pragma unroll
          for (int j = 0; j < 8; j++) { h0[j] = (_Float16)src[j]; h1[j] = (_Float16)src[8 + j]; }
          *(f16x8*)dst = h0; *(f16x8*)(dst + 8) = h1;
        } else {                              // fp16: raw copy
          uint4 v0 = *(const uint4*)src;
          uint4 v1 = *(const uint4*)(src + 8);
          *(uint4*)dst = v0; *(uint4*)(dst + 8) = v1;
        }
      } else {
        *(uint4*)dst = make_uint4(0, 0, 0, 0);
        *(uint4*)(dst + 8) = make_uint4(0, 0, 0, 0);
      }
    }
    // ---- stage W hi/lo: PT rows x 32 halves each ----
    for (int idx = tid; idx < PT * 2; idx += 256) {
      int isL = idx >= PT;
      int p = isL ? idx - PT : idx;
      const _Float16* src = (isL ? WtL : WtH) + (size_t)p * K + kc * 32;
      _Float16* dst = (isL ? WsL : WsH) + p * 32;
      uint4 a0 = *(const uint4*)src;       uint4 a1 = *(const uint4*)(src + 8);
      uint4 a2 = *(const uint4*)(src + 16); uint4 a3 = *(const uint4*)(src + 24);
      *(uint4*)dst = a0; *(uint4*)(dst + 8) = a1;
      *(uint4*)(dst + 16) = a2; *(uint4*)(dst + 24) = a3;
    }
    __syncthreads();

    f16x8 bh[CTB], bl[CTB], bhE, blE;
#pragma unroll
    for (int nt = 0; nt < CTB; nt++) {
      int p = (wave * CTB + nt) * 16 + l16;
      bh[nt] = *(f16x8*)&WsH[p * 32 + quad * 8];
      bl[nt] = *(f16x8*)&WsL[p * 32 + quad * 8];
    }
    if (xw) {
      int p = 4 * CTB * 16 + l16;
      bhE = *(f16x8*)&WsH[p * 32 + quad * 8];
      blE = *(f16x8*)&WsL[p * 32 + quad * 8];
    }
#pragma unroll
    for (int rt = 0; rt < 8; rt++) {
      f16x8 a = *(f16x8*)&As[(rt * 16 + l16) * 32 + quad * 8];
#pragma unroll
      for (int nt = 0; nt < CTB; nt++) {
        acc[rt][nt] = __builtin_amdgcn_mfma_f32_16x16x32_f16(a, bh[nt], acc[rt][nt], 0, 0, 0);
        acc[rt][nt] = __builtin_amdgcn_mfma_f32_16x16x32_f16(a, bl[nt], acc[rt][nt], 0, 0, 0);
      }
      if (xw) {
        acc[rt][CTB] = __builtin_amdgcn_mfma_f32_16x16x32_f16(a, bhE, acc[rt][CTB], 0, 0, 0);
        acc[rt][CTB] = __builtin_amdgcn_mfma_f32_16x16x32_f16(a, blE, acc[rt][CTB], 0, 0, 0);
      }
    }
    __syncthreads();
  }

  // ---- epilogue (C/D layout: col=lane&15, row=quad*4+reg) ----
#pragma unroll
  for (int nt = 0; nt < CTB; nt++) {
    int c = (wave * CTB + nt) * 16 + l16;
#pragma unroll
    for (int rt = 0; rt < 8; rt++)
#pragma unroll
      for (int g = 0; g < 4; g++) {
        int r = row0 + rt * 16 + quad * 4 + g;
        if (r < N) C[(size_t)r * PST + c] = (_Float16)acc[rt][nt][g];
      }
  }
  if (wave == 0 && l16 < 8) {
    float* dstb = (l16 < 4) ? esb : edb;
    int h = l16 & 3;
#pragma unroll
    for (int rt = 0; rt < 8; rt++)
#pragma unroll
      for (int g = 0; g < 4; g++) {
        int r = row0 + rt * 16 + quad * 4 + g;
        if (r < N) dstb[(size_t)r * 4 + h] = acc[rt][CTB][g];
      }
  }
}

// ---------------- fused MLP: out = bn2(relu(bn1(relu(A@M1+b1))@M2+b2)) ----------------
__global__ __launch_bounds__(256) void mlp_fused(
    const _Float16* __restrict__ A,
    const _Float16* __restrict__ M1H, const _Float16* __restrict__ M1L,
    const _Float16* __restrict__ M2H, const _Float16* __restrict__ M2L,
    _Float16* __restrict__ C, int N,
    const float* __restrict__ b1v, const float* __restrict__ g1v, const float* __restrict__ be1v,
    const float* __restrict__ b2v, const float* __restrict__ g2v, const float* __restrict__ be2v) {
  __shared__ _Float16 As[128 * 32];
  __shared__ _Float16 W1Hs[64 * 32], W1Ls[64 * 32];
  __shared__ _Float16 T[128 * 72];          // +8 pad halves per row
  __shared__ _Float16 W2Hs[128 * 32], W2Ls[128 * 32];
  const int tid = threadIdx.x;
  const int wave = tid >> 6, lane = tid & 63;
  const int quad = lane >> 4, l16 = lane & 15;
  const int row0 = blockIdx.x * 128;

  // ---- GEMM 1: [128x128] @ [128x64] ----
  f32x4 acc1[8];
#pragma unroll
  for (int rt = 0; rt < 8; rt++) acc1[rt] = (f32x4){0.f, 0.f, 0.f, 0.f};
  for (int kc = 0; kc < 4; ++kc) {
    {
      int r = tid >> 1, part = tid & 1;
      int gr = row0 + r;
      _Float16* dst = &As[r * 32 + part * 16];
      if (gr < N) {
        const _Float16* src = A + (size_t)gr * 128 + kc * 32 + part * 16;
        uint4 v0 = *(const uint4*)src;
        uint4 v1 = *(const uint4*)(src + 8);
        *(uint4*)dst = v0; *(uint4*)(dst + 8) = v1;
      } else {
        *(uint4*)dst = make_uint4(0, 0, 0, 0);
        *(uint4*)(dst + 8) = make_uint4(0, 0, 0, 0);
      }
    }
    if (tid < 128) {
      int isL = tid >= 64;
      int p = tid & 63;
      const _Float16* src = (isL ? M1L : M1H) + (size_t)p * 128 + kc * 32;
      _Float16* dst = (isL ? W1Ls : W1Hs) + p * 32;
      uint4 a0 = *(const uint4*)src;       uint4 a1 = *(const uint4*)(src + 8);
      uint4 a2 = *(const uint4*)(src + 16); uint4 a3 = *(const uint4*)(src + 24);
      *(uint4*)dst = a0; *(uint4*)(dst + 8) = a1;
      *(uint4*)(dst + 16) = a2; *(uint4*)(dst + 24) = a3;
    }
    __syncthreads();
    int p = wave * 16 + l16;
    f16x8 bh = *(f16x8*)&W1Hs[p * 32 + quad * 8];
    f16x8 bl = *(f16x8*)&W1Ls[p * 32 + quad * 8];
#pragma unroll
    for (int rt = 0; rt < 8; rt++) {
      f16x8 a = *(f16x8*)&As[(rt * 16 + l16) * 32 + quad * 8];
      acc1[rt] = __builtin_amdgcn_mfma_f32_16x16x32_f16(a, bh, acc1[rt], 0, 0, 0);
      acc1[rt] = __builtin_amdgcn_mfma_f32_16x16x32_f16(a, bl, acc1[rt], 0, 0, 0);
    }
    __syncthreads();
  }
  {
    int c = wave * 16 + l16;
    float bi = b1v[c], ga = g1v[c] * BN_RS, be = be1v[c];
#pragma unroll
    for (int rt = 0; rt < 8; rt++)
#pragma unroll
      for (int g = 0; g < 4; g++) {
        int r = rt * 16 + quad * 4 + g;
        float v = acc1[rt][g] + bi;
        v = v > 0.f ? v : 0.f;
        v = v * ga + be;
        T[r * 72 + c] = (_Float16)v;
      }
  }
  __syncthreads();

  // ---- GEMM 2: T[128x64] @ [64x128] ----
  f32x4 acc2[8][2];
#pragma unroll
  for (int rt = 0; rt < 8; rt++)
#pragma unroll
    for (int nt = 0; nt < 2; nt++) acc2[rt][nt] = (f32x4){0.f, 0.f, 0.f, 0.f};
  for (int kc = 0; kc < 2; ++kc) {
    {
      int isL = tid >= 128;
      int p = tid & 127;
      const _Float16* src = (isL ? M2L : M2H) + (size_t)p * 64 + kc * 32;
      _Float16* dst = (isL ? W2Ls : W2Hs) + p * 32;
      uint4 a0 = *(const uint4*)src;       uint4 a1 = *(const uint4*)(src + 8);
      uint4 a2 = *(const uint4*)(src + 16); uint4 a3 = *(const uint4*)(src + 24);
      *(uint4*)dst = a0; *(uint4*)(dst + 8) = a1;
      *(uint4*)(dst + 16) = a2; *(uint4*)(dst + 24) = a3;
    }
    __syncthreads();
    f16x8 bh[2], bl[2];
#pragma unroll
    for (int nt = 0; nt < 2; nt++) {
      int p = (wave * 2 + nt) * 16 + l16;
      bh[nt] = *(f16x8*)&W2Hs[p * 32 + quad * 8];
      bl[nt] = *(f16x8*)&W2Ls[p * 32 + quad * 8];
    }
#pragma unroll
    for (int rt = 0; rt < 8; rt++) {
      f16x8 a = *(f16x8*)&T[(rt * 16 + l16) * 72 + kc * 32 + quad * 8];
#pragma unroll
      for (int nt = 0; nt < 2; nt++) {
        acc2[rt][nt] = __builtin_amdgcn_mfma_f32_16x16x32_f16(a, bh[nt], acc2[rt][nt], 0, 0, 0);
        acc2[rt][nt] = __builtin_amdgcn_mfma_f32_16x16x32_f16(a, bl[nt], acc2[rt][nt], 0, 0, 0);
      }
    }
    __syncthreads();
  }
#pragma unroll
  for (int nt = 0; nt < 2; nt++) {
    int c = (wave * 2 + nt) * 16 + l16;
    float bi = b2v[c], ga = g2v[c] * BN_RS, be = be2v[c];
#pragma unroll
    for (int rt = 0; rt < 8; rt++)
#pragma unroll
      for (int g = 0; g < 4; g++) {
        int r = row0 + rt * 16 + quad * 4 + g;
        if (r < N) {
          float v = acc2[rt][nt][g] + bi;
          v = v > 0.f ? v : 0.f;
          v = v * ga + be;
          C[(size_t)r * 128 + c] = (_Float16)v;
        }
      }
  }
}

// ---------------- GAT aggregation: 4 nodes/wave, 16 lanes/node, 16B/lane loads ----------
// Group g = lane>>4 owns node nid; lane il=lane&15 holds features il*8..il*8+7 (head il>>2).
// One global load instr covers 4 edges x 256B = 1KB -> 8x more bytes in flight.
// Phase 1 (per 16-edge chunk): lane il computes all 4 heads' w of slot il (one float4 es
// load + 4 exp) into double-buffered LDS. Phase 2: 4-wide unrolled f16x8 row gathers.
// MODE 0: out fp16 [N,128] = relu(S/z + bias). MODE 1: out fp32 [N,32] = mean_heads + bias.
template <int MODE>
__global__ __launch_bounds__(256) void gat_agg(
    const _Float16* __restrict__ hx, const int* __restrict__ rowptr,
    const unsigned* __restrict__ csr, const float* __restrict__ es,
    const float* __restrict__ ed, const float* __restrict__ bias,
    void* __restrict__ outp, int N) {
  __shared__ float4 wbuf[4][4][2][17];   // [wave][group][buf][slot(16)+pad]
  __shared__ int    sbuf[4][4][2][16];
  const int tid = threadIdx.x;
  const int wave = tid >> 6, lane = tid & 63;
  const int g = lane >> 4, il = lane & 15;
  const int hd = il >> 2;
  const int nid = (blockIdx.x * 4 + wave) * 4 + g;
  const bool valid = (nid < N);
  int beg = 0, end = 0;
  if (valid) { beg = rowptr[nid]; end = rowptr[nid + 1]; }
  float4 edv = make_float4(0.f, 0.f, 0.f, 0.f);
  if (valid) edv = *(const float4*)(ed + (size_t)nid * 4);
  float acc[8];
#pragma unroll
  for (int r = 0; r < 8; r++) acc[r] = 0.f;
  float z = 0.f;
  const _Float16* hb = hx + il * 8;
  const int nch = (end - beg + 15) >> 4;

  // prologue: chunk-0 weights
  {
    int m = end - beg; if (m > 16) m = 16;
    if (il < m) {
      int s = (int)(csr[beg + il] & 0xFFFFu);
      float4 e4 = *(const float4*)(es + (size_t)s * 4);
      float t0 = e4.x + edv.x, t1 = e4.y + edv.y;
      float t2 = e4.z + edv.z, t3 = e4.w + edv.w;
      t0 = t0 > 0.f ? t0 : NEG_SLOPE * t0;
      t1 = t1 > 0.f ? t1 : NEG_SLOPE * t1;
      t2 = t2 > 0.f ? t2 : NEG_SLOPE * t2;
      t3 = t3 > 0.f ? t3 : NEG_SLOPE * t3;
      wbuf[wave][g][0][il] = make_float4(__expf(t0), __expf(t1), __expf(t2), __expf(t3));
      sbuf[wave][g][0][il] = s;
    }
  }
  int pb = 0;
  for (int ci = 0; ci < nch; ++ci) {
    int c = beg + (ci << 4);
    int m = end - c; if (m > 16) m = 16;
    if (ci + 1 < nch) {                 // prefetch next chunk's weights
      int c2 = c + 16;
      int m2 = end - c2; if (m2 > 16) m2 = 16;
      if (il < m2) {
        int s = (int)(csr[c2 + il] & 0xFFFFu);
        float4 e4 = *(const float4*)(es + (size_t)s * 4);
        float t0 = e4.x + edv.x, t1 = e4.y + edv.y;
        float t2 = e4.z + edv.z, t3 = e4.w + edv.w;
        t0 = t0 > 0.f ? t0 : NEG_SLOPE * t0;
        t1 = t1 > 0.f ? t1 : NEG_SLOPE * t1;
        t2 = t2 > 0.f ? t2 : NEG_SLOPE * t2;
        t3 = t3 > 0.f ? t3 : NEG_SLOPE * t3;
        wbuf[wave][g][pb ^ 1][il] = make_float4(__expf(t0), __expf(t1), __expf(t2), __expf(t3));
        sbuf[wave][g][pb ^ 1][il] = s;
      }
    }
    const float* wp = (const float*)&wbuf[wave][g][pb][0];
    const int*   sp = &sbuf[wave][g][pb][0];
    int j = 0;
    for (; j + 4 <= m; j += 4) {
      int s0 = sp[j], s1 = sp[j + 1], s2 = sp[j + 2], s3 = sp[j + 3];
      float w0 = wp[(j + 0) * 4 + hd], w1 = wp[(j + 1) * 4 + hd];
      float w2 = wp[(j + 2) * 4 + hd], w3 = wp[(j + 3) * 4 + hd];
      f16x8 r0 = *(const f16x8*)(hb + (size_t)s0 * 128);
      f16x8 r1 = *(const f16x8*)(hb + (size_t)s1 * 128);
      f16x8 r2 = *(const f16x8*)(hb + (size_t)s2 * 128);
      f16x8 r3 = *(const f16x8*)(hb + (size_t)s3 * 128);
      z += (w0 + w1) + (w2 + w3);
#pragma unroll
      for (int r = 0; r < 8; r++) {
        float a = acc[r];
        a = fmaf(w0, (float)r0[r], a);
        a = fmaf(w1, (float)r1[r], a);
        a = fmaf(w2, (float)r2[r], a);
        a = fmaf(w3, (float)r3[r], a);
        acc[r] = a;
      }
    }
    for (; j < m; ++j) {
      int s = sp[j];
      float w = wp[j * 4 + hd];
      f16x8 rv = *(const f16x8*)(hb + (size_t)s * 128);
      z += w;
#pragma unroll
      for (int r = 0; r < 8; r++) acc[r] = fmaf(w, (float)rv[r], acc[r]);
    }
    pb ^= 1;
  }
  float inv = 1.f / (z + 1e-16f);
  if (MODE == 0) {
    f16x8 o;
#pragma unroll
    for (int r = 0; r < 8; r++) {
      float v = acc[r] * inv + bias[il * 8 + r];
      v = v > 0.f ? v : 0.f;
      o[r] = (_Float16)v;
    }
    if (valid) *(f16x8*)((_Float16*)outp + (size_t)nid * 128 + il * 8) = o;
  } else {
    float v[8];
#pragma unroll
    for (int r = 0; r < 8; r++) {
      float t = acc[r] * inv;
      t += __shfl_xor(t, 4);
      t += __shfl_xor(t, 8);
      v[r] = t;
    }
    if (valid && il < 4) {              // lane q=il writes outputs p = il*8 + r
      float4 o0, o1;
      o0.x = v[0] * 0.25f + bias[il * 8 + 0];
      o0.y = v[1] * 0.25f + bias[il * 8 + 1];
      o0.z = v[2] * 0.25f + bias[il * 8 + 2];
      o0.w = v[3] * 0.25f + bias[il * 8 + 3];
      o1.x = v[4] * 0.25f + bias[il * 8 + 4];
      o1.y = v[5] * 0.25f + bias[il * 8 + 5];
      o1.z = v[6] * 0.25f + bias[il * 8 + 6];
      o1.w = v[7] * 0.25f + bias[il * 8 + 7];
      *(float4*)((float*)outp + (size_t)nid * 32 + il * 8) = o0;
      *(float4*)((float*)outp + (size_t)nid * 32 + il * 8 + 4) = o1;
    }
  }
}

extern "C" void kernel_launch(void* const* d_in, const int* in_sizes, int n_in,
                              void* d_out, int out_size, void* d_ws, size_t ws_size,
                              hipStream_t stream) {
  const float* x   = (const float*)d_in[0];
  const int*   ei  = (const int*)d_in[1];
  const float* W1  = (const float*)d_in[2];
  const float* a1s = (const float*)d_in[3];
  const float* a1d = (const float*)d_in[4];
  const float* b1  = (const float*)d_in[5];
  const float* W2  = (const float*)d_in[6];
  const float* a2s = (const float*)d_in[7];
  const float* a2d = (const float*)d_in[8];
  const float* b2  = (const float*)d_in[9];
  const float* M1w = (const float*)d_in[10];
  const float* M1b = (const float*)d_in[11];
  const float* g1  = (const float*)d_in[12];
  const float* be1 = (const float*)d_in[13];
  const float* M2w = (const float*)d_in[14];
  const float* M2b = (const float*)d_in[15];
  const float* g2  = (const float*)d_in[16];
  const float* be2 = (const float*)d_in[17];
  const float* W3  = (const float*)d_in[18];
  const float* a3s = (const float*)d_in[19];
  const float* a3d = (const float*)d_in[20];
  const float* b3  = (const float*)d_in[21];

  const int N = in_sizes[0] / 128;
  const int E = in_sizes[1] / 2;
  const int S = E + N;                 // csr slots (edges + self-loops)

  char* w = (char*)d_ws;
  _Float16* bufA = (_Float16*)w; w += (size_t)N * 128 * 2;
  _Float16* bufB = (_Float16*)w; w += (size_t)N * 128 * 2;
  float* esb  = (float*)w; w += (size_t)N * 4 * 4;
  float* edb  = (float*)w; w += (size_t)N * 4 * 4;
  int* rowptr = (int*)w;   w += (size_t)(N + 1) * 4;
  unsigned* csr = (unsigned*)w; w += (size_t)S * 4;
  unsigned* staging = (unsigned*)w; w += (size_t)E * 4;
  int* bucketSize = (int*)w; w += 256 * 4;
  int* edgeStart  = (int*)w; w += 257 * 4;
  int* cursor     = (int*)w; w += 256 * 4;
  int* csrStart   = (int*)w; w += 256 * 4;
  // split-fp16 transposed weights (hi/lo)
  _Float16* W1H = (_Float16*)w; w += 144 * 128 * 2;
  _Float16* W1L = (_Float16*)w; w += 144 * 128 * 2;
  _Float16* W2H = (_Float16*)w; w += 144 * 128 * 2;
  _Float16* W2L = (_Float16*)w; w += 144 * 128 * 2;
  _Float16* W3H = (_Float16*)w; w += 144 * 128 * 2;
  _Float16* W3L = (_Float16*)w; w += 144 * 128 * 2;
  _Float16* M1H = (_Float16*)w; w += 64 * 128 * 2;
  _Float16* M1L = (_Float16*)w; w += 64 * 128 * 2;
  _Float16* M2H = (_Float16*)w; w += 128 * 64 * 2;
  _Float16* M2L = (_Float16*)w; w += 128 * 64 * 2;

  const int gb = (N + 127) / 128;
  const int aggb = (N + 15) / 16;      // 16 nodes per block (4 waves x 4 groups)
  const int nbk = (N + 255) / 256;     // buckets
  const int pbk = (E + PCH - 1) / PCH;

  // ---- weight prep + bucketSize zero (single dispatch) ----
  wprep_all<<<281, 256, 0, stream>>>(W1, a1s, a1d, W1H, W1L,
                                     W2, a2s, a2d, W2H, W2L,
                                     W3, a3s, a3d, W3H, W3L,
                                     M1w, M1H, M1L, M2w, M2H, M2L, bucketSize);

  // ---- CSR build: bucket radix partition ----
  eb_hist<<<256, 256, 0, stream>>>(ei, bucketSize, E);
  eb_scan<<<1, 256, 0, stream>>>(bucketSize, edgeStart, cursor, csrStart, N);
  eb_part<<<pbk, 256, 0, stream>>>(ei, cursor, staging, E);
  eb_csr<<<nbk, 256, 0, stream>>>(staging, edgeStart, csrStart, rowptr, csr, N);

  // ---- layer 0: conv0(+attn) -> agg(relu+bias) -> fused MLP ----
  gemm_f16<float><<<gb, 256, 0, stream>>>(x, W1H, W1L, bufA, N, esb, edb);
  gat_agg<0><<<aggb, 256, 0, stream>>>(bufA, rowptr, csr, esb, edb, b1, bufB, N);
  mlp_fused<<<gb, 256, 0, stream>>>(bufB, M1H, M1L, M2H, M2L, bufA, N,
                                    M1b, g1, be1, M2b, g2, be2);

  // ---- layer 1: conv1(+attn) -> agg(relu+bias) ----
  gemm_f16<_Float16><<<gb, 256, 0, stream>>>(bufA, W2H, W2L, bufB, N, esb, edb);
  gat_agg<0><<<aggb, 256, 0, stream>>>(bufB, rowptr, csr, esb, edb, b2, bufA, N);

  // ---- layer 2: conv2(+attn) -> agg (mean heads, +b3) ----
  gemm_f16<_Float16><<<gb, 256, 0, stream>>>(bufA, W3H, W3L, bufB, N, esb, edb);
  gat_agg<1><<<aggb, 256, 0, stream>>>(bufB, rowptr, csr, esb, edb, b3, d_out, N);
}